// Round 4
// baseline (808.808 us; speedup 1.0000x reference)
//
#include <hip/hip_runtime.h>
#include <stdint.h>

// ---------------------------------------------------------------------------
// MoE top-2: gating (fp64 logits, LDS-staged w_gate) -> grouped bf16 MFMA FFN
//            -> logsumexp combine
// B=8192 D=3072 E=8 H=2048 O=512 K=2
// GEMM1 = 256x128 tile, BK=64, 2-buffer issue-early prefetch (minimum-2-phase
// recipe: __syncthreads-only sync, compiler-managed waits), T2 LDS swizzle,
// XCD-chunked block remap.
// Round 4: resubmission of round-2 content (+ cnte<=0 guard). Rounds 1-3 all
// died at container level incl. the barrier-only r2/r3 kernel -> dominant
// hypothesis is a wedged fleet node, not kernel content. Bisect plan: if this
// fails again, round 5 submits the byte-exact round-0 baseline as infra probe.
// ---------------------------------------------------------------------------

typedef __bf16 bf16x8 __attribute__((ext_vector_type(8)));
typedef __bf16 bf16x4 __attribute__((ext_vector_type(4)));
typedef float floatx4 __attribute__((ext_vector_type(4)));

#define EPSF 2.2204460492503131e-16f

__device__ __forceinline__ void gl_lds16(const void* g, void* l) {
  __builtin_amdgcn_global_load_lds(
      (__attribute__((address_space(1))) void*)(g),
      (__attribute__((address_space(3))) void*)(l), 16, 0, 0);
}

// ---------------- gating: 8 rows/block, w_gate staged in LDS ---------------
__global__ __launch_bounds__(512) void k_gating(
    const float* __restrict__ x, const float* __restrict__ wg,
    __bf16* __restrict__ x_bf, int* __restrict__ expsel,
    float* __restrict__ gpair) {
  __shared__ float wgs[12320];  // 1536*8 + 8*4 pad words = 49.3 KB
  const int tid = threadIdx.x;
  const int lane = tid & 63;
  const int w = tid >> 6;                 // wave 0..7 -> row
  const int r = blockIdx.x * 8 + w;
  const int g = lane >> 3;                // d-chunk 0..7
  const int e = lane & 7;                 // expert
  const float* xr = x + (size_t)r * 3072;
  __bf16* xbr = x_bf + (size_t)r * 3072;

#pragma unroll
  for (int t = 0; t < 12; ++t) {
    const int d = t * 256 + lane * 4;
    const float4 xv = *(const float4*)(xr + d);
    bf16x4 xo;
    xo.x = (__bf16)xv.x; xo.y = (__bf16)xv.y;
    xo.z = (__bf16)xv.z; xo.w = (__bf16)xv.w;
    *(bf16x4*)(xbr + d) = xo;
  }

  double a0 = 0.0, a1 = 0.0;
  for (int h = 0; h < 2; ++h) {
    __syncthreads();
#pragma unroll
    for (int t = 0; t < 6; ++t) {
      const int wi = t * 2048 + tid * 4;
      const int gg = wi / 1536;
      const float4 v = *(const float4*)(wg + h * 12288 + wi);
      *(float4*)(wgs + wi + 4 * gg) = v;
    }
    __syncthreads();
    const float* xrg = xr + h * 1536 + g * 192;
    const float* wbase = wgs + g * 1540 + e;
    for (int i = 0; i < 192; i += 4) {
      const float4 xv = *(const float4*)(xrg + i);
      a0 += (double)xv.x * (double)wbase[(i + 0) * 8];
      a1 += (double)xv.y * (double)wbase[(i + 1) * 8];
      a0 += (double)xv.z * (double)wbase[(i + 2) * 8];
      a1 += (double)xv.w * (double)wbase[(i + 3) * 8];
    }
  }
  double v = a0 + a1;
  v += __shfl_xor(v, 8);
  v += __shfl_xor(v, 16);
  v += __shfl_xor(v, 32);
  double le[8];
#pragma unroll
  for (int ee = 0; ee < 8; ++ee) le[ee] = __shfl(v, ee);
  if (lane == 0) {
    int i0 = 0; double v0 = le[0];
#pragma unroll
    for (int k = 1; k < 8; ++k) if (le[k] > v0) { v0 = le[k]; i0 = k; }
    int i1 = (i0 == 0) ? 1 : 0; double v1 = le[i1];
#pragma unroll
    for (int k = 0; k < 8; ++k)
      if (k != i0 && le[k] > v1 && k != i1) { v1 = le[k]; i1 = k; }
    const float tt = (float)exp(v1 - v0);
    const float g0 = 1.0f / (1.0f + tt);
    const float g1 = tt / (1.0f + tt);
    expsel[r] = i0 | (i1 << 4);
    gpair[r * 2] = g0;
    gpair[r * 2 + 1] = g1;
  }
}

// ---------------- gating phase B: ordered compaction per expert ------------
__global__ __launch_bounds__(256) void k_build_lists(
    const int* __restrict__ expsel, const float* __restrict__ gpair,
    int* __restrict__ lists, int* __restrict__ cnt, double* __restrict__ imp) {
  const int e = blockIdx.x;
  const int tid = threadIdx.x;
  const int lane = tid & 63;
  const int w = tid >> 6;
  __shared__ int wsum[4];
  __shared__ double dsum[4];
  int base = 0;
  double gsum = 0.0;
  int* out = lists + e * 8192;
  for (int c = 0; c < 32; ++c) {
    const int r = c * 256 + tid;
    const int sel = expsel[r];
    const bool m0 = ((sel & 15) == e);
    const bool m1 = (((sel >> 4) & 15) == e);
    const bool m = m0 || m1;
    const int entry = 2 * r + (m1 ? 1 : 0);
    const unsigned long long mask = __ballot(m);
    const int wcount = __popcll(mask);
    const int pos = __popcll(mask & ((1ull << lane) - 1ull));
    if (lane == 0) wsum[w] = wcount;
    __syncthreads();
    int pre = base;
#pragma unroll
    for (int ww = 0; ww < 4; ++ww) if (ww < w) pre += wsum[ww];
    const int total = wsum[0] + wsum[1] + wsum[2] + wsum[3];
    if (m) {
      out[pre + pos] = entry;
      gsum += (double)gpair[entry];
    }
    base += total;
    __syncthreads();
  }
  gsum += __shfl_down(gsum, 32);
  gsum += __shfl_down(gsum, 16);
  gsum += __shfl_down(gsum, 8);
  gsum += __shfl_down(gsum, 4);
  gsum += __shfl_down(gsum, 2);
  gsum += __shfl_down(gsum, 1);
  if (lane == 0) dsum[w] = gsum;
  __syncthreads();
  if (tid == 0) {
    imp[e] = dsum[0] + dsum[1] + dsum[2] + dsum[3];
    cnt[e] = base;
  }
}

// ---------------- tile schedules + aux loss --------------------------------
__global__ void k_sched_aux(const int* __restrict__ cnt, const double* __restrict__ imp,
                            int* __restrict__ sched, int* __restrict__ nslots,
                            int* __restrict__ sched2, int* __restrict__ nslots2,
                            float* __restrict__ aux_out) {
  if (threadIdx.x != 0 || blockIdx.x != 0) return;
  int ns = 0, ns2 = 0;
  for (int e = 0; e < 8; ++e) {
    const int c = cnt[e];
    const int t = (c + 127) >> 7;
    for (int i = 0; i < t; ++i) { sched[2 * ns] = e; sched[2 * ns + 1] = i << 7; ++ns; }
    const int t2 = (c + 255) >> 8;
    for (int i = 0; i < t2; ++i) { sched2[2 * ns2] = e; sched2[2 * ns2 + 1] = i << 8; ++ns2; }
  }
  *nslots = ns;
  *nslots2 = ns2;
  double mi = 0.0, ml = 0.0;
  for (int e = 0; e < 8; ++e) { mi += imp[e]; ml += (double)cnt[e]; }
  mi *= 0.125; ml *= 0.125;
  double vi = 0.0, vl = 0.0;
  for (int e = 0; e < 8; ++e) {
    const double di = imp[e] - mi; vi += di * di;
    const double dl = (double)cnt[e] - ml; vl += dl * dl;
  }
  vi /= 7.0; vl /= 7.0;
  aux_out[0] = (float)(0.01 * (vi / (mi * mi + 1e-10) + vl / (ml * ml + 1e-10)));
}

// ---------------- (E,R,C) fp32 -> (E,C,R) bf16 transpose, 64x64 tiles ------
__global__ __launch_bounds__(256) void k_transpose_cvt(
    const float* __restrict__ in, __bf16* __restrict__ out, int R, int C) {
  __shared__ float tile[64][65];
  const int e = blockIdx.z;
  const int c0 = blockIdx.x * 64;
  const int r0 = blockIdx.y * 64;
  const float* src = in + (size_t)e * R * C + (size_t)r0 * C + c0;
  __bf16* dst = out + (size_t)e * R * C + (size_t)c0 * R + r0;
  const int tx = threadIdx.x & 15;
  const int ty = threadIdx.x >> 4;
#pragma unroll
  for (int i = 0; i < 4; ++i) {
    const int row = ty + i * 16;
    const float4 v = *(const float4*)(src + (size_t)row * C + tx * 4);
    tile[row][tx * 4 + 0] = v.x;
    tile[row][tx * 4 + 1] = v.y;
    tile[row][tx * 4 + 2] = v.z;
    tile[row][tx * 4 + 3] = v.w;
  }
  __syncthreads();
#pragma unroll
  for (int i = 0; i < 4; ++i) {
    const int cc = ty + i * 16;
    const int rr = tx * 4;
    bf16x4 o;
    o.x = (__bf16)tile[rr + 0][cc];
    o.y = (__bf16)tile[rr + 1][cc];
    o.z = (__bf16)tile[rr + 2][cc];
    o.w = (__bf16)tile[rr + 3][cc];
    *(bf16x4*)(dst + (size_t)cc * R + rr) = o;
  }
}

// ---------------- GEMM1: 256x128 tile, BK=64, 2-buf issue-early prefetch ---
// h = relu(Xg @ W1t^T + b1) -> bf16 h_pairs[p][0..2048)
// 8 waves (4M x 2N); per-wave 64x64 output; LDS 2 x (A[256][64] + B[128][64]).
// Per K-tile: __syncthreads (drains tile kt's 6 in-flight loads — the only
// outstanding VMEM, so the full drain IS the counted wait) -> issue STAGE of
// tile kt+1 into the other buffer -> ds_read + MFMA tile kt. Staging latency
// hides under the current tile's MFMA phase. Sync is __syncthreads-only;
// control flow fully uniform.
// Swizzle (T2, both-sides): stage pre-swizzles the GLOBAL source k-chunk
// (kc = (lane&7) ^ lr) since global_load_lds writes LDS linearly; the ds_read
// applies the same involution (chunk ^ (row&7)) -> fragment reads <=2-way.
// Buffer-reuse: STAGE(kt+1) writes buf (kt+1)&1, whose readers were at
// iteration kt-1; their ds_reads drained at the top-of-kt __syncthreads.
template <int KDIM>
__global__ __launch_bounds__(512, 2) void k_moe_gemm256(
    const __bf16* __restrict__ Asrc, const __bf16* __restrict__ Ball,
    const float* __restrict__ bias, const int* __restrict__ lists,
    const int* __restrict__ cnt, const int* __restrict__ sched,
    const int* __restrict__ nslots, __bf16* __restrict__ hout) {
  constexpr int NT = KDIM / 64;
  __shared__ __bf16 lds2[2 * 24576];  // per buf: A @0 (16384), B @16384 (8192)

  // XCD-chunked bijective remap (m204): a slot's 16 n-tiles share one XCD.
  const int nwg = gridDim.x * gridDim.y;  // gridDim.x == 16
  int lin = blockIdx.y * gridDim.x + blockIdx.x;
  const int q = nwg >> 3, r = nwg & 7;
  const int xcd = lin & 7, idx = lin >> 3;
  lin = (xcd < r) ? (xcd * (q + 1) + idx) : (r * (q + 1) + (xcd - r) * q + idx);
  const int slot = lin >> 4;
  const int ntile = lin & 15;
  if (slot >= *nslots) return;

  const int e = sched[2 * slot];
  const int row0 = sched[2 * slot + 1];
  const int cnte = cnt[e];
  if (cnte <= 0) return;  // defensive: never reached with this gating
  const int n0 = ntile * 128;

  const int tid = threadIdx.x;
  const int lane = tid & 63;
  const int w = __builtin_amdgcn_readfirstlane(tid >> 6);
  const int wm = w >> 1;            // 0..3 : 64-row block
  const int wn = w & 1;             // 0..1 : 64-col block
  const int lr = lane >> 3;         // 0..7 : row within 8-row stripe
  const int kc = (lane & 7) ^ lr;   // pre-swizzled source k-chunk

  const __bf16* Be = Ball + (size_t)e * 2048 * KDIM;
  const int* liste = lists + e * 8192;

  const __bf16* aptr[4];
#pragma unroll
  for (int j = 0; j < 4; ++j) {
    int m = row0 + w * 32 + j * 8 + lr;
    m = (m < cnte) ? m : (cnte - 1);        // clamp ragged edge
    aptr[j] = Asrc + (size_t)(liste[m] >> 1) * KDIM + kc * 8;
  }
  const __bf16* bptr[2];
#pragma unroll
  for (int j = 0; j < 2; ++j)
    bptr[j] = Be + (size_t)(n0 + w * 16 + j * 8 + lr) * KDIM + kc * 8;

  floatx4 acc[4][4];
#pragma unroll
  for (int i = 0; i < 4; ++i)
#pragma unroll
    for (int j = 0; j < 4; ++j) {
      acc[i][j].x = 0.f; acc[i][j].y = 0.f; acc[i][j].z = 0.f; acc[i][j].w = 0.f;
    }

  auto STAGE = [&](int buf, int kt) {
    __bf16* base = lds2 + buf * 24576;
    const int ko = kt * 64;
#pragma unroll
    for (int j = 0; j < 4; ++j)
      gl_lds16(aptr[j] + ko, base + (w * 32 + j * 8) * 64);
#pragma unroll
    for (int j = 0; j < 2; ++j)
      gl_lds16(bptr[j] + ko, base + 16384 + (w * 16 + j * 8) * 64);
  };

  STAGE(0, 0);

  const int frow = lane & 15;
  const int fr7 = lane & 7;
  const int fch = lane >> 4;  // 0..3 -> 16B chunk within 32-k substep
  const int axo0 = ((fch) ^ fr7) * 8;
  const int axo1 = ((4 + fch) ^ fr7) * 8;

  for (int kt = 0; kt < NT; ++kt) {
    __syncthreads();                         // tile kt's loads landed
    if (kt + 1 < NT) STAGE((kt + 1) & 1, kt + 1);
    const __bf16* Abuf = lds2 + (kt & 1) * 24576;
    const __bf16* Bbuf = Abuf + 16384;
    bf16x8 bfr[2][4];
#pragma unroll
    for (int j = 0; j < 4; ++j) {
      const __bf16* brow = Bbuf + (wn * 64 + j * 16 + frow) * 64;
      bfr[0][j] = *(const bf16x8*)(brow + axo0);
      bfr[1][j] = *(const bf16x8*)(brow + axo1);
    }
#pragma unroll
    for (int i = 0; i < 4; ++i) {
      const __bf16* arow = Abuf + (wm * 64 + i * 16 + frow) * 64;
      const bf16x8 a0 = *(const bf16x8*)(arow + axo0);
      const bf16x8 a1 = *(const bf16x8*)(arow + axo1);
#pragma unroll
      for (int j = 0; j < 4; ++j) {
        acc[i][j] = __builtin_amdgcn_mfma_f32_16x16x32_bf16(a0, bfr[0][j], acc[i][j], 0, 0, 0);
        acc[i][j] = __builtin_amdgcn_mfma_f32_16x16x32_bf16(a1, bfr[1][j], acc[i][j], 0, 0, 0);
      }
    }
  }

  // epilogue: C/D layout col=lane&15, row=(lane>>4)*4+reg  [measured m89/m91]
  const int cq = lane >> 4;
  const int cn = lane & 15;
#pragma unroll
  for (int i = 0; i < 4; ++i) {
#pragma unroll
    for (int rr = 0; rr < 4; ++rr) {
      const int m = row0 + wm * 64 + i * 16 + cq * 4 + rr;
      if (m < cnte) {
        const int p = liste[m];
        __bf16* orow = hout + (size_t)p * 2048;
#pragma unroll
        for (int j = 0; j < 4; ++j) {
          const int n = n0 + wn * 64 + j * 16 + cn;
          float v = acc[i][j][rr] + bias[e * 2048 + n];
          orow[n] = (__bf16)(v > 0.0f ? v : 0.0f);
        }
      }
    }
  }
}

// ---------------- GEMM2 (m97 gemm_bt structure, gathered A) ----------------
// MODE 1: op = gpair[p] * exp(Hg @ W2t^T + b2) -> fp32 out_pairs[p][0..512)
template <int KDIM, int MODE>
__global__ __launch_bounds__(256, 2) void k_moe_gemm(
    const __bf16* __restrict__ Asrc, const __bf16* __restrict__ Ball,
    const float* __restrict__ bias, const int* __restrict__ lists,
    const int* __restrict__ cnt, const int* __restrict__ sched,
    const int* __restrict__ nslots, const float* __restrict__ gpair,
    __bf16* __restrict__ hout, float* __restrict__ oout) {
  constexpr int NDIM = (MODE == 0) ? 2048 : 512;
  const int slot = blockIdx.y;
  if (slot >= *nslots) return;
  const int e = sched[2 * slot];
  const int row0 = sched[2 * slot + 1];
  const int cnte = cnt[e];
  if (cnte <= 0) return;  // defensive
  const int n0 = blockIdx.x * 128;

  __shared__ unsigned short As[128 * 32];
  __shared__ unsigned short Bs[128 * 32];

  const int tid = threadIdx.x;
  const int lane = tid & 63;
  const int wid = __builtin_amdgcn_readfirstlane(tid >> 6);
  const int wm = wid >> 1;
  const int wn = wid & 1;

  const __bf16* Be = Ball + (size_t)e * NDIM * KDIM;
  const int* liste = lists + e * 8192;
  const int acol = (lane & 3) * 8;

  const __bf16* aptr[2];
  const __bf16* bptr[2];
#pragma unroll
  for (int p = 0; p < 2; ++p) {
    const int chunk = wid + 4 * p;
    const int lr = chunk * 16 + (lane >> 2);
    int m = row0 + lr;
    m = (m < cnte) ? m : (cnte - 1);
    const int entry = liste[m];
    const int srow = (MODE == 0) ? (entry >> 1) : entry;
    aptr[p] = Asrc + (size_t)srow * KDIM + acol;
    bptr[p] = Be + (size_t)(n0 + lr) * KDIM + acol;
  }

  floatx4 acc[4][4];
#pragma unroll
  for (int i = 0; i < 4; ++i)
#pragma unroll
    for (int j = 0; j < 4; ++j) {
      acc[i][j].x = 0.f; acc[i][j].y = 0.f; acc[i][j].z = 0.f; acc[i][j].w = 0.f;
    }

  for (int k0 = 0; k0 < KDIM; k0 += 32) {
#pragma unroll
    for (int p = 0; p < 2; ++p) {
      gl_lds16(aptr[p] + k0, &As[(wid + 4 * p) * 512]);
      gl_lds16(bptr[p] + k0, &Bs[(wid + 4 * p) * 512]);
    }
    __syncthreads();
    bf16x8 af[4], bfr[4];
    const int rdoff = (lane & 15) * 32 + (lane >> 4) * 8;
#pragma unroll
    for (int i = 0; i < 4; ++i)
      af[i] = *(const bf16x8*)&As[(wm * 64 + i * 16) * 32 + rdoff];
#pragma unroll
    for (int j = 0; j < 4; ++j)
      bfr[j] = *(const bf16x8*)&Bs[(wn * 64 + j * 16) * 32 + rdoff];
    __syncthreads();
#pragma unroll
    for (int i = 0; i < 4; ++i)
#pragma unroll
      for (int j = 0; j < 4; ++j)
        acc[i][j] = __builtin_amdgcn_mfma_f32_16x16x32_bf16(af[i], bfr[j], acc[i][j], 0, 0, 0);
  }

  const int cq = lane >> 4;
  const int cn = lane & 15;
#pragma unroll
  for (int i = 0; i < 4; ++i) {
#pragma unroll
    for (int r = 0; r < 4; ++r) {
      const int m = row0 + wm * 64 + i * 16 + cq * 4 + r;
      if (m < cnte) {
        const int p = liste[m];
        if (MODE == 0) {
          __bf16* orow = hout + (size_t)p * 2048;
#pragma unroll
          for (int j = 0; j < 4; ++j) {
            const int n = n0 + wn * 64 + j * 16 + cn;
            float v = acc[i][j][r] + bias[e * 2048 + n];
            v = v > 0.0f ? v : 0.0f;
            orow[n] = (__bf16)v;
          }
        } else {
          float* orow = oout + (size_t)p * 512;
          const float g = gpair[p];
#pragma unroll
          for (int j = 0; j < 4; ++j) {
            const int n = n0 + wn * 64 + j * 16 + cn;
            const float v = acc[i][j][r] + bias[e * 512 + n];
            orow[n] = g * __expf(v);
          }
        }
      }
    }
  }
}

// ---------------- combine: y[r] = log(op[2r] + op[2r+1]) -------------------
__global__ __launch_bounds__(128) void k_combine(const float* __restrict__ op,
                                                 float* __restrict__ y) {
  const int r = blockIdx.x;
  const int o = threadIdx.x * 4;
  const float4 a = *(const float4*)(op + (size_t)(2 * r) * 512 + o);
  const float4 b = *(const float4*)(op + (size_t)(2 * r + 1) * 512 + o);
  float4 res;
  float s;
  s = a.x + b.x; if (s == 0.0f) s = EPSF; res.x = logf(s);
  s = a.y + b.y; if (s == 0.0f) s = EPSF; res.y = logf(s);
  s = a.z + b.z; if (s == 0.0f) s = EPSF; res.z = logf(s);
  s = a.w + b.w; if (s == 0.0f) s = EPSF; res.w = logf(s);
  *(float4*)(y + (size_t)r * 512 + o) = res;
}

// ---------------------------------------------------------------------------
extern "C" void kernel_launch(void* const* d_in, const int* in_sizes, int n_in,
                              void* d_out, int out_size, void* d_ws, size_t ws_size,
                              hipStream_t stream) {
  (void)in_sizes; (void)n_in; (void)out_size; (void)ws_size;
  const float* x  = (const float*)d_in[0];
  // d_in[1] = Cats (unused by reference)
  const float* wg = (const float*)d_in[2];
  const float* W1 = (const float*)d_in[3];
  const float* b1 = (const float*)d_in[4];
  const float* W2 = (const float*)d_in[5];
  const float* b2 = (const float*)d_in[6];
  float* y = (float*)d_out;

  // workspace carve (~269 MB)
  char* w = (char*)d_ws;
  __bf16* x_bf = (__bf16*)w; w += (size_t)8192 * 3072 * 2;        // 50.3 MB
  __bf16* w1t  = (__bf16*)w; w += (size_t)8 * 2048 * 3072 * 2;    // 100.7 MB (E,H,D)
  __bf16* w2t  = (__bf16*)w; w += (size_t)8 * 512 * 2048 * 2;     // 16.8 MB (E,O,H)
  __bf16* hp   = (__bf16*)w; w += (size_t)16384 * 2048 * 2;       // 67.1 MB pair-h
  float*  op   = (float*)w;  w += (size_t)16384 * 512 * 4;        // 33.6 MB pair-out
  int*    lists= (int*)w;    w += (size_t)8 * 8192 * 4;           // expert row lists
  float*  gpr  = (float*)w;  w += (size_t)16384 * 4;              // gate per pair
  int*    expsel=(int*)w;    w += (size_t)8192 * 4;               // e0 | e1<<4 per row
  int*    cnt  = (int*)w;    w += 64;
  double* imp  = (double*)w; w += 64;
  int*    sched= (int*)w;    w += 2 * 136 * 4;
  int*    nslots=(int*)w;    w += 64;
  int*    sched2=(int*)w;    w += 2 * 72 * 4;
  int*    nslots2=(int*)w;   w += 64;

  hipLaunchKernelGGL(k_gating, dim3(1024), dim3(512), 0, stream, x, wg, x_bf, expsel, gpr);
  hipLaunchKernelGGL(k_build_lists, dim3(8), dim3(256), 0, stream, expsel, gpr, lists, cnt, imp);
  hipLaunchKernelGGL(k_transpose_cvt, dim3(32, 48, 8), dim3(256), 0, stream, W1, w1t, 3072, 2048);
  hipLaunchKernelGGL(k_transpose_cvt, dim3(8, 32, 8), dim3(256), 0, stream, W2, w2t, 2048, 512);
  hipLaunchKernelGGL(k_sched_aux, dim3(1), dim3(64), 0, stream, cnt, imp, sched, nslots,
                     sched2, nslots2, y + (size_t)8192 * 512);
  hipLaunchKernelGGL((k_moe_gemm256<3072>), dim3(16, 72), dim3(512), 0, stream,
                     x_bf, w1t, b1, lists, cnt, sched2, nslots2, hp);
  hipLaunchKernelGGL((k_moe_gemm<2048, 1>), dim3(4, 136), dim3(256), 0, stream,
                     hp, w2t, b2, lists, cnt, sched, nslots, gpr,
                     (__bf16*)nullptr, op);
  hipLaunchKernelGGL(k_combine, dim3(8192), dim3(128), 0, stream, op, y);
}

// Round 5
// 772.545 us; speedup vs baseline: 1.0469x; 1.0469x over previous
//
#include <hip/hip_runtime.h>
#include <stdint.h>

// ---------------------------------------------------------------------------
// MoE top-2: gating (fp64 logits, LDS-staged w_gate) -> grouped bf16 MFMA FFN
//            -> logsumexp combine
// B=8192 D=3072 E=8 H=2048 O=512 K=2
// GEMM1 = 256x256 tile, BK=64, m201-style 4-phase/K-tile fine interleave with
// counted vmcnt(4) (never 0 in steady state), K-half LDS layout, both-sides
// swizzle, setprio around MFMA clusters, XCD-chunked remap.
// ---------------------------------------------------------------------------

typedef __bf16 bf16x8 __attribute__((ext_vector_type(8)));
typedef __bf16 bf16x4 __attribute__((ext_vector_type(4)));
typedef float floatx4 __attribute__((ext_vector_type(4)));

#define EPSF 2.2204460492503131e-16f

__device__ __forceinline__ void gl_lds16(const void* g, void* l) {
  __builtin_amdgcn_global_load_lds(
      (__attribute__((address_space(1))) void*)(g),
      (__attribute__((address_space(3))) void*)(l), 16, 0, 0);
}

// ---------------- gating: 8 rows/block, w_gate staged in LDS ---------------
__global__ __launch_bounds__(512) void k_gating(
    const float* __restrict__ x, const float* __restrict__ wg,
    __bf16* __restrict__ x_bf, int* __restrict__ expsel,
    float* __restrict__ gpair) {
  __shared__ float wgs[12320];  // 1536*8 + 8*4 pad words = 49.3 KB
  const int tid = threadIdx.x;
  const int lane = tid & 63;
  const int w = tid >> 6;                 // wave 0..7 -> row
  const int r = blockIdx.x * 8 + w;
  const int g = lane >> 3;                // d-chunk 0..7
  const int e = lane & 7;                 // expert
  const float* xr = x + (size_t)r * 3072;
  __bf16* xbr = x_bf + (size_t)r * 3072;

#pragma unroll
  for (int t = 0; t < 12; ++t) {
    const int d = t * 256 + lane * 4;
    const float4 xv = *(const float4*)(xr + d);
    bf16x4 xo;
    xo.x = (__bf16)xv.x; xo.y = (__bf16)xv.y;
    xo.z = (__bf16)xv.z; xo.w = (__bf16)xv.w;
    *(bf16x4*)(xbr + d) = xo;
  }

  double a0 = 0.0, a1 = 0.0;
  for (int h = 0; h < 2; ++h) {
    __syncthreads();
#pragma unroll
    for (int t = 0; t < 6; ++t) {
      const int wi = t * 2048 + tid * 4;
      const int gg = wi / 1536;
      const float4 v = *(const float4*)(wg + h * 12288 + wi);
      *(float4*)(wgs + wi + 4 * gg) = v;
    }
    __syncthreads();
    const float* xrg = xr + h * 1536 + g * 192;
    const float* wbase = wgs + g * 1540 + e;
    for (int i = 0; i < 192; i += 4) {
      const float4 xv = *(const float4*)(xrg + i);
      a0 += (double)xv.x * (double)wbase[(i + 0) * 8];
      a1 += (double)xv.y * (double)wbase[(i + 1) * 8];
      a0 += (double)xv.z * (double)wbase[(i + 2) * 8];
      a1 += (double)xv.w * (double)wbase[(i + 3) * 8];
    }
  }
  double v = a0 + a1;
  v += __shfl_xor(v, 8);
  v += __shfl_xor(v, 16);
  v += __shfl_xor(v, 32);
  double le[8];
#pragma unroll
  for (int ee = 0; ee < 8; ++ee) le[ee] = __shfl(v, ee);
  if (lane == 0) {
    int i0 = 0; double v0 = le[0];
#pragma unroll
    for (int k = 1; k < 8; ++k) if (le[k] > v0) { v0 = le[k]; i0 = k; }
    int i1 = (i0 == 0) ? 1 : 0; double v1 = le[i1];
#pragma unroll
    for (int k = 0; k < 8; ++k)
      if (k != i0 && le[k] > v1 && k != i1) { v1 = le[k]; i1 = k; }
    const float tt = (float)exp(v1 - v0);
    const float g0 = 1.0f / (1.0f + tt);
    const float g1 = tt / (1.0f + tt);
    expsel[r] = i0 | (i1 << 4);
    gpair[r * 2] = g0;
    gpair[r * 2 + 1] = g1;
  }
}

// ---------------- gating phase B: ordered compaction per expert ------------
__global__ __launch_bounds__(256) void k_build_lists(
    const int* __restrict__ expsel, const float* __restrict__ gpair,
    int* __restrict__ lists, int* __restrict__ cnt, double* __restrict__ imp) {
  const int e = blockIdx.x;
  const int tid = threadIdx.x;
  const int lane = tid & 63;
  const int w = tid >> 6;
  __shared__ int wsum[4];
  __shared__ double dsum[4];
  int base = 0;
  double gsum = 0.0;
  int* out = lists + e * 8192;
  for (int c = 0; c < 32; ++c) {
    const int r = c * 256 + tid;
    const int sel = expsel[r];
    const bool m0 = ((sel & 15) == e);
    const bool m1 = (((sel >> 4) & 15) == e);
    const bool m = m0 || m1;
    const int entry = 2 * r + (m1 ? 1 : 0);
    const unsigned long long mask = __ballot(m);
    const int wcount = __popcll(mask);
    const int pos = __popcll(mask & ((1ull << lane) - 1ull));
    if (lane == 0) wsum[w] = wcount;
    __syncthreads();
    int pre = base;
#pragma unroll
    for (int ww = 0; ww < 4; ++ww) if (ww < w) pre += wsum[ww];
    const int total = wsum[0] + wsum[1] + wsum[2] + wsum[3];
    if (m) {
      out[pre + pos] = entry;
      gsum += (double)gpair[entry];
    }
    base += total;
    __syncthreads();
  }
  gsum += __shfl_down(gsum, 32);
  gsum += __shfl_down(gsum, 16);
  gsum += __shfl_down(gsum, 8);
  gsum += __shfl_down(gsum, 4);
  gsum += __shfl_down(gsum, 2);
  gsum += __shfl_down(gsum, 1);
  if (lane == 0) dsum[w] = gsum;
  __syncthreads();
  if (tid == 0) {
    imp[e] = dsum[0] + dsum[1] + dsum[2] + dsum[3];
    cnt[e] = base;
  }
}

// ---------------- tile schedules + aux loss --------------------------------
__global__ void k_sched_aux(const int* __restrict__ cnt, const double* __restrict__ imp,
                            int* __restrict__ sched, int* __restrict__ nslots,
                            int* __restrict__ sched2, int* __restrict__ nslots2,
                            float* __restrict__ aux_out) {
  if (threadIdx.x != 0 || blockIdx.x != 0) return;
  int ns = 0, ns2 = 0;
  for (int e = 0; e < 8; ++e) {
    const int c = cnt[e];
    const int t = (c + 127) >> 7;
    for (int i = 0; i < t; ++i) { sched[2 * ns] = e; sched[2 * ns + 1] = i << 7; ++ns; }
    const int t2 = (c + 255) >> 8;
    for (int i = 0; i < t2; ++i) { sched2[2 * ns2] = e; sched2[2 * ns2 + 1] = i << 8; ++ns2; }
  }
  *nslots = ns;
  *nslots2 = ns2;
  double mi = 0.0, ml = 0.0;
  for (int e = 0; e < 8; ++e) { mi += imp[e]; ml += (double)cnt[e]; }
  mi *= 0.125; ml *= 0.125;
  double vi = 0.0, vl = 0.0;
  for (int e = 0; e < 8; ++e) {
    const double di = imp[e] - mi; vi += di * di;
    const double dl = (double)cnt[e] - ml; vl += dl * dl;
  }
  vi /= 7.0; vl /= 7.0;
  aux_out[0] = (float)(0.01 * (vi / (mi * mi + 1e-10) + vl / (ml * ml + 1e-10)));
}

// ---------------- (E,R,C) fp32 -> (E,C,R) bf16 transpose, 64x64 tiles ------
__global__ __launch_bounds__(256) void k_transpose_cvt(
    const float* __restrict__ in, __bf16* __restrict__ out, int R, int C) {
  __shared__ float tile[64][65];
  const int e = blockIdx.z;
  const int c0 = blockIdx.x * 64;
  const int r0 = blockIdx.y * 64;
  const float* src = in + (size_t)e * R * C + (size_t)r0 * C + c0;
  __bf16* dst = out + (size_t)e * R * C + (size_t)c0 * R + r0;
  const int tx = threadIdx.x & 15;
  const int ty = threadIdx.x >> 4;
#pragma unroll
  for (int i = 0; i < 4; ++i) {
    const int row = ty + i * 16;
    const float4 v = *(const float4*)(src + (size_t)row * C + tx * 4);
    tile[row][tx * 4 + 0] = v.x;
    tile[row][tx * 4 + 1] = v.y;
    tile[row][tx * 4 + 2] = v.z;
    tile[row][tx * 4 + 3] = v.w;
  }
  __syncthreads();
#pragma unroll
  for (int i = 0; i < 4; ++i) {
    const int cc = ty + i * 16;
    const int rr = tx * 4;
    bf16x4 o;
    o.x = (__bf16)tile[rr + 0][cc];
    o.y = (__bf16)tile[rr + 1][cc];
    o.z = (__bf16)tile[rr + 2][cc];
    o.w = (__bf16)tile[rr + 3][cc];
    *(bf16x4*)(dst + (size_t)cc * R + rr) = o;
  }
}

// ---------------- GEMM1: 256x256, BK=64, 4-phase fine interleave -----------
// h = relu(Xg @ W1t^T + b1) -> bf16 h_pairs[p][0..2048)
// 8 waves (2M x 4N); per-wave 128x64 output; LDS 2 buf x {A_s0,A_s1,B_s0,B_s1}
// each half = 256 rows x 32 k bf16 (16 KB), buffer 64 KB, total 128 KB.
// Phases per K-tile kt (cur=kt&1):
//   p0: rd A[s0][i0-3](4) + B[s0][j0-3](4); stage As0(kt+1); 16 MFMA (i0-3,s0)
//   p1: rd A[s0][i4-7](4);                  stage Bs0(kt+1); 16 MFMA (i4-7,s0)
//       tail: vmcnt(4) (last tile: 0) -> Khalf1(kt) landed
//   p2: rd A[s1][i4-7](4) + B[s1][j0-3](4); stage As1(kt+1); 16 MFMA (i4-7,s1)
//   p3: rd A[s1][i0-3](4);                  stage Bs1(kt+1); 16 MFMA (i0-3,s1)
//       tail: vmcnt(4) -> Khalf0(kt+1) landed for next p0
// Each phase: issues; s_barrier; sched_barrier; setprio(1); MFMA; setprio(0);
// [tail vmcnt]; s_barrier; sched_barrier. Barriers unconditional & uniform.
// Staging targets buf cur^1 (holds tile kt-1, fully read: its readers' lgkm
// completed before their MFMA barriers, which all waves passed). vmcnt counts
// are per-wave-closed: every thread issues exactly 2 loads per half-tile in
// fixed order As0,Bs0,As1,Bs1.
// Swizzle (both-sides involution): LDS slot chunk c holds global chunk
// c ^ ((row>>1)&3); stage pre-swizzles the global source column; reads use
// fch ^ ((frow>>1)&3). gl_lds dest is wave-uniform base + lane*16 (linear).
template <int KDIM>
__global__ __launch_bounds__(512, 2) void k_moe_gemm256(
    const __bf16* __restrict__ Asrc, const __bf16* __restrict__ Ball,
    const float* __restrict__ bias, const int* __restrict__ lists,
    const int* __restrict__ cnt, const int* __restrict__ sched,
    const int* __restrict__ nslots, __bf16* __restrict__ hout) {
  constexpr int NT = KDIM / 64;           // 48 K-tiles
  __shared__ __bf16 lds[2 * 32768];       // 128 KB

  // XCD-chunked bijective remap (m204)
  const int nwg = gridDim.x * gridDim.y;  // 8 * 72
  int lin = blockIdx.y * gridDim.x + blockIdx.x;
  const int q = nwg >> 3, rr8 = nwg & 7;
  const int xcd = lin & 7, bidx = lin >> 3;
  lin = (xcd < rr8) ? (xcd * (q + 1) + bidx) : (rr8 * (q + 1) + (xcd - rr8) * q + bidx);
  const int slot = lin >> 3;              // 8 n-tiles of 256
  const int ntile = lin & 7;
  if (slot >= *nslots) return;

  const int e = sched[2 * slot];
  const int row0 = sched[2 * slot + 1];
  const int cnte = cnt[e];
  if (cnte <= 0) return;
  const int n0 = ntile * 256;

  const int tid = threadIdx.x;
  const int lane = tid & 63;
  const int w = __builtin_amdgcn_readfirstlane(tid >> 6);
  const int wm = w >> 2;                  // 0..1 : 128-row block
  const int wn = w & 3;                   // 0..3 : 64-col block

  const int* liste = lists + e * 8192;
  const __bf16* Be = Ball + (size_t)e * 2048 * KDIM;

  // staging state: thread covers rows rt0 (issue 0) and rt1 (issue 1)
  const int rt0 = tid >> 2;
  const int rt1 = 128 + rt0;
  const __bf16* agrow[2];
  const __bf16* bgrow[2];
  {
    int m0 = row0 + rt0; m0 = (m0 < cnte) ? m0 : (cnte - 1);
    int m1 = row0 + rt1; m1 = (m1 < cnte) ? m1 : (cnte - 1);
    agrow[0] = Asrc + (size_t)(liste[m0] >> 1) * KDIM;
    agrow[1] = Asrc + (size_t)(liste[m1] >> 1) * KDIM;
    bgrow[0] = Be + (size_t)(n0 + rt0) * KDIM;
    bgrow[1] = Be + (size_t)(n0 + rt1) * KDIM;
  }
  const int csw = ((tid & 3) ^ ((rt0 >> 1) & 3)) * 8;  // same for rt1 (+128 rows)
  const int wdst = w * 512;               // wave-uniform LDS chunk (elems)

  // STAGE one half-tile (isB, s) of K-tile kt into buffer buf: 2 loads/thread
  auto STAGE = [&](int buf, int kt, int isB, int s) {
    const int ko = kt * 64 + s * 32 + csw;
    const int dbase = buf * 32768 + isB * 16384 + s * 8192 + wdst;
    gl_lds16((isB ? bgrow[0] : agrow[0]) + ko, lds + dbase);
    gl_lds16((isB ? bgrow[1] : agrow[1]) + ko, lds + dbase + 4096);
  };

  // fragment read bases (elems)
  const int frow = lane & 15;
  const int fch = lane >> 4;
  const int rsw = (frow >> 1) & 3;
  const int aRd = (wm * 128 + frow) * 32 + (fch ^ rsw) * 8;
  const int bRd = 16384 + (wn * 64 + frow) * 32 + (fch ^ rsw) * 8;

  floatx4 acc[8][4];
#pragma unroll
  for (int i = 0; i < 8; ++i)
#pragma unroll
    for (int j = 0; j < 4; ++j) {
      acc[i][j].x = 0.f; acc[i][j].y = 0.f; acc[i][j].z = 0.f; acc[i][j].w = 0.f;
    }

  // prologue: tile 0, per-thread issue order As0,Bs0,As1,Bs1
  STAGE(0, 0, 0, 0);
  STAGE(0, 0, 1, 0);
  STAGE(0, 0, 0, 1);
  STAGE(0, 0, 1, 1);
  asm volatile("s_waitcnt vmcnt(4)" ::: "memory");  // tile0 Khalf0 landed
  __builtin_amdgcn_s_barrier();
  __builtin_amdgcn_sched_barrier(0);

  bf16x8 bf[4];
  for (int kt = 0; kt < NT; ++kt) {
    const int cur = kt & 1, nxt = cur ^ 1;
    const __bf16* Ab = lds + cur * 32768;
    const bool st = (kt + 1 < NT);

    // ---- p0: A[s0][i0-3] + B[s0], stage As0(kt+1), MFMA (i0-3, s0) ----
    {
      bf16x8 af[4];
#pragma unroll
      for (int i = 0; i < 4; ++i) af[i] = *(const bf16x8*)(Ab + aRd + i * 512);
#pragma unroll
      for (int j = 0; j < 4; ++j) bf[j] = *(const bf16x8*)(Ab + bRd + j * 512);
      if (st) STAGE(nxt, kt + 1, 0, 0);
      __builtin_amdgcn_s_barrier();
      __builtin_amdgcn_sched_barrier(0);
      __builtin_amdgcn_s_setprio(1);
#pragma unroll
      for (int i = 0; i < 4; ++i)
#pragma unroll
        for (int j = 0; j < 4; ++j)
          acc[i][j] = __builtin_amdgcn_mfma_f32_16x16x32_bf16(af[i], bf[j], acc[i][j], 0, 0, 0);
      __builtin_amdgcn_s_setprio(0);
      __builtin_amdgcn_s_barrier();
      __builtin_amdgcn_sched_barrier(0);
    }
    // ---- p1: A[s0][i4-7], stage Bs0(kt+1), MFMA (i4-7, s0); tail vmcnt ----
    {
      bf16x8 af[4];
#pragma unroll
      for (int i = 0; i < 4; ++i) af[i] = *(const bf16x8*)(Ab + aRd + (4 + i) * 512);
      if (st) STAGE(nxt, kt + 1, 1, 0);
      __builtin_amdgcn_s_barrier();
      __builtin_amdgcn_sched_barrier(0);
      __builtin_amdgcn_s_setprio(1);
#pragma unroll
      for (int i = 0; i < 4; ++i)
#pragma unroll
        for (int j = 0; j < 4; ++j)
          acc[4 + i][j] = __builtin_amdgcn_mfma_f32_16x16x32_bf16(af[i], bf[j], acc[4 + i][j], 0, 0, 0);
      __builtin_amdgcn_s_setprio(0);
      if (st) { asm volatile("s_waitcnt vmcnt(4)" ::: "memory"); }
      else    { asm volatile("s_waitcnt vmcnt(0)" ::: "memory"); }
      __builtin_amdgcn_s_barrier();
      __builtin_amdgcn_sched_barrier(0);
    }
    // ---- p2: A[s1][i4-7] + B[s1], stage As1(kt+1), MFMA (i4-7, s1) ----
    {
      bf16x8 af[4];
#pragma unroll
      for (int i = 0; i < 4; ++i) af[i] = *(const bf16x8*)(Ab + 8192 + aRd + (4 + i) * 512);
#pragma unroll
      for (int j = 0; j < 4; ++j) bf[j] = *(const bf16x8*)(Ab + 8192 + bRd + j * 512);
      if (st) STAGE(nxt, kt + 1, 0, 1);
      __builtin_amdgcn_s_barrier();
      __builtin_amdgcn_sched_barrier(0);
      __builtin_amdgcn_s_setprio(1);
#pragma unroll
      for (int i = 0; i < 4; ++i)
#pragma unroll
        for (int j = 0; j < 4; ++j)
          acc[4 + i][j] = __builtin_amdgcn_mfma_f32_16x16x32_bf16(af[i], bf[j], acc[4 + i][j], 0, 0, 0);
      __builtin_amdgcn_s_setprio(0);
      __builtin_amdgcn_s_barrier();
      __builtin_amdgcn_sched_barrier(0);
    }
    // ---- p3: A[s1][i0-3], stage Bs1(kt+1), MFMA (i0-3, s1); tail vmcnt ----
    {
      bf16x8 af[4];
#pragma unroll
      for (int i = 0; i < 4; ++i) af[i] = *(const bf16x8*)(Ab + 8192 + aRd + i * 512);
      if (st) STAGE(nxt, kt + 1, 1, 1);
      __builtin_amdgcn_s_barrier();
      __builtin_amdgcn_sched_barrier(0);
      __builtin_amdgcn_s_setprio(1);
#pragma unroll
      for (int i = 0; i < 4; ++i)
#pragma unroll
        for (int j = 0; j < 4; ++j)
          acc[i][j] = __builtin_amdgcn_mfma_f32_16x16x32_bf16(af[i], bf[j], acc[i][j], 0, 0, 0);
      __builtin_amdgcn_s_setprio(0);
      asm volatile("s_waitcnt vmcnt(4)" ::: "memory");  // next tile Khalf0
      __builtin_amdgcn_s_barrier();
      __builtin_amdgcn_sched_barrier(0);
    }
  }

  // epilogue: C/D layout col=lane&15, row=(lane>>4)*4+reg  [measured m89/m91]
  const int cq = lane >> 4;
  const int cn = lane & 15;
#pragma unroll
  for (int i = 0; i < 8; ++i) {
#pragma unroll
    for (int rr = 0; rr < 4; ++rr) {
      const int m = row0 + wm * 128 + i * 16 + cq * 4 + rr;
      if (m < cnte) {
        const int p = liste[m];
        __bf16* orow = hout + (size_t)p * 2048;
#pragma unroll
        for (int j = 0; j < 4; ++j) {
          const int n = n0 + wn * 64 + j * 16 + cn;
          float v = acc[i][j][rr] + bias[e * 2048 + n];
          orow[n] = (__bf16)(v > 0.0f ? v : 0.0f);
        }
      }
    }
  }
}

// ---------------- GEMM2 (m97 gemm_bt structure, gathered A) ----------------
// MODE 1: op = gpair[p] * exp(Hg @ W2t^T + b2) -> fp32 out_pairs[p][0..512)
template <int KDIM, int MODE>
__global__ __launch_bounds__(256, 2) void k_moe_gemm(
    const __bf16* __restrict__ Asrc, const __bf16* __restrict__ Ball,
    const float* __restrict__ bias, const int* __restrict__ lists,
    const int* __restrict__ cnt, const int* __restrict__ sched,
    const int* __restrict__ nslots, const float* __restrict__ gpair,
    __bf16* __restrict__ hout, float* __restrict__ oout) {
  constexpr int NDIM = (MODE == 0) ? 2048 : 512;
  const int slot = blockIdx.y;
  if (slot >= *nslots) return;
  const int e = sched[2 * slot];
  const int row0 = sched[2 * slot + 1];
  const int cnte = cnt[e];
  if (cnte <= 0) return;  // defensive
  const int n0 = blockIdx.x * 128;

  __shared__ unsigned short As[128 * 32];
  __shared__ unsigned short Bs[128 * 32];

  const int tid = threadIdx.x;
  const int lane = tid & 63;
  const int wid = __builtin_amdgcn_readfirstlane(tid >> 6);
  const int wm = wid >> 1;
  const int wn = wid & 1;

  const __bf16* Be = Ball + (size_t)e * NDIM * KDIM;
  const int* liste = lists + e * 8192;
  const int acol = (lane & 3) * 8;

  const __bf16* aptr[2];
  const __bf16* bptr[2];
#pragma unroll
  for (int p = 0; p < 2; ++p) {
    const int chunk = wid + 4 * p;
    const int lr = chunk * 16 + (lane >> 2);
    int m = row0 + lr;
    m = (m < cnte) ? m : (cnte - 1);
    const int entry = liste[m];
    const int srow = (MODE == 0) ? (entry >> 1) : entry;
    aptr[p] = Asrc + (size_t)srow * KDIM + acol;
    bptr[p] = Be + (size_t)(n0 + lr) * KDIM + acol;
  }

  floatx4 acc[4][4];
#pragma unroll
  for (int i = 0; i < 4; ++i)
#pragma unroll
    for (int j = 0; j < 4; ++j) {
      acc[i][j].x = 0.f; acc[i][j].y = 0.f; acc[i][j].z = 0.f; acc[i][j].w = 0.f;
    }

  for (int k0 = 0; k0 < KDIM; k0 += 32) {
#pragma unroll
    for (int p = 0; p < 2; ++p) {
      gl_lds16(aptr[p] + k0, &As[(wid + 4 * p) * 512]);
      gl_lds16(bptr[p] + k0, &Bs[(wid + 4 * p) * 512]);
    }
    __syncthreads();
    bf16x8 af[4], bfr[4];
    const int rdoff = (lane & 15) * 32 + (lane >> 4) * 8;
#pragma unroll
    for (int i = 0; i < 4; ++i)
      af[i] = *(const bf16x8*)&As[(wm * 64 + i * 16) * 32 + rdoff];
#pragma unroll
    for (int j = 0; j < 4; ++j)
      bfr[j] = *(const bf16x8*)&Bs[(wn * 64 + j * 16) * 32 + rdoff];
    __syncthreads();
#pragma unroll
    for (int i = 0; i < 4; ++i)
#pragma unroll
      for (int j = 0; j < 4; ++j)
        acc[i][j] = __builtin_amdgcn_mfma_f32_16x16x32_bf16(af[i], bfr[j], acc[i][j], 0, 0, 0);
  }

  const int cq = lane >> 4;
  const int cn = lane & 15;
#pragma unroll
  for (int i = 0; i < 4; ++i) {
#pragma unroll
    for (int r = 0; r < 4; ++r) {
      const int m = row0 + wm * 64 + i * 16 + cq * 4 + r;
      if (m < cnte) {
        const int p = liste[m];
        if (MODE == 0) {
          __bf16* orow = hout + (size_t)p * 2048;
#pragma unroll
          for (int j = 0; j < 4; ++j) {
            const int n = n0 + wn * 64 + j * 16 + cn;
            float v = acc[i][j][r] + bias[e * 2048 + n];
            v = v > 0.0f ? v : 0.0f;
            orow[n] = (__bf16)v;
          }
        } else {
          float* orow = oout + (size_t)p * 512;
          const float g = gpair[p];
#pragma unroll
          for (int j = 0; j < 4; ++j) {
            const int n = n0 + wn * 64 + j * 16 + cn;
            const float v = acc[i][j][r] + bias[e * 512 + n];
            orow[n] = g * __expf(v);
          }
        }
      }
    }
  }
}

// ---------------- combine: y[r] = log(op[2r] + op[2r+1]) -------------------
__global__ __launch_bounds__(128) void k_combine(const float* __restrict__ op,
                                                 float* __restrict__ y) {
  const int r = blockIdx.x;
  const int o = threadIdx.x * 4;
  const float4 a = *(const float4*)(op + (size_t)(2 * r) * 512 + o);
  const float4 b = *(const float4*)(op + (size_t)(2 * r + 1) * 512 + o);
  float4 res;
  float s;
  s = a.x + b.x; if (s == 0.0f) s = EPSF; res.x = logf(s);
  s = a.y + b.y; if (s == 0.0f) s = EPSF; res.y = logf(s);
  s = a.z + b.z; if (s == 0.0f) s = EPSF; res.z = logf(s);
  s = a.w + b.w; if (s == 0.0f) s = EPSF; res.w = logf(s);
  *(float4*)(y + (size_t)r * 512 + o) = res;
}

// ---------------------------------------------------------------------------
extern "C" void kernel_launch(void* const* d_in, const int* in_sizes, int n_in,
                              void* d_out, int out_size, void* d_ws, size_t ws_size,
                              hipStream_t stream) {
  (void)in_sizes; (void)n_in; (void)out_size; (void)ws_size;
  const float* x  = (const float*)d_in[0];
  // d_in[1] = Cats (unused by reference)
  const float* wg = (const float*)d_in[2];
  const float* W1 = (const float*)d_in[3];
  const float* b1 = (const float*)d_in[4];
  const float* W2 = (const float*)d_in[5];
  const float* b2 = (const float*)d_in[6];
  float* y = (float*)d_out;

  // workspace carve (~269 MB)
  char* w = (char*)d_ws;
  __bf16* x_bf = (__bf16*)w; w += (size_t)8192 * 3072 * 2;        // 50.3 MB
  __bf16* w1t  = (__bf16*)w; w += (size_t)8 * 2048 * 3072 * 2;    // 100.7 MB (E,H,D)
  __bf16* w2t  = (__bf16*)w; w += (size_t)8 * 512 * 2048 * 2;     // 16.8 MB (E,O,H)
  __bf16* hp   = (__bf16*)w; w += (size_t)16384 * 2048 * 2;       // 67.1 MB pair-h
  float*  op   = (float*)w;  w += (size_t)16384 * 512 * 4;        // 33.6 MB pair-out
  int*    lists= (int*)w;    w += (size_t)8 * 8192 * 4;           // expert row lists
  float*  gpr  = (float*)w;  w += (size_t)16384 * 4;              // gate per pair
  int*    expsel=(int*)w;    w += (size_t)8192 * 4;               // e0 | e1<<4 per row
  int*    cnt  = (int*)w;    w += 64;
  double* imp  = (double*)w; w += 64;
  int*    sched= (int*)w;    w += 2 * 136 * 4;
  int*    nslots=(int*)w;    w += 64;
  int*    sched2=(int*)w;    w += 2 * 72 * 4;
  int*    nslots2=(int*)w;   w += 64;

  hipLaunchKernelGGL(k_gating, dim3(1024), dim3(512), 0, stream, x, wg, x_bf, expsel, gpr);
  hipLaunchKernelGGL(k_build_lists, dim3(8), dim3(256), 0, stream, expsel, gpr, lists, cnt, imp);
  hipLaunchKernelGGL(k_transpose_cvt, dim3(32, 48, 8), dim3(256), 0, stream, W1, w1t, 3072, 2048);
  hipLaunchKernelGGL(k_transpose_cvt, dim3(8, 32, 8), dim3(256), 0, stream, W2, w2t, 2048, 512);
  hipLaunchKernelGGL(k_sched_aux, dim3(1), dim3(64), 0, stream, cnt, imp, sched, nslots,
                     sched2, nslots2, y + (size_t)8192 * 512);
  hipLaunchKernelGGL((k_moe_gemm256<3072>), dim3(8, 72), dim3(512), 0, stream,
                     x_bf, w1t, b1, lists, cnt, sched2, nslots2, hp);
  hipLaunchKernelGGL((k_moe_gemm<2048, 1>), dim3(4, 136), dim3(256), 0, stream,
                     hp, w2t, b2, lists, cnt, sched, nslots, gpr,
                     (__bf16*)nullptr, op);
  hipLaunchKernelGGL(k_combine, dim3(8192), dim3(128), 0, stream, op, y);
}